// Round 1
// baseline (398.274 us; speedup 1.0000x reference)
//
#include <hip/hip_runtime.h>
#include <stdint.h>

// DropBlock: x:(64,64,112,112) f32. mask over (B,H,W) from JAX threefry
// bernoulli(seed 42), eroded by 6x6 min window (pad (2,3)), out = x*mask * N/sum.
#define B_      64
#define C_      64
#define H_      112
#define W_      112
#define HW_     12544      // H*W
#define NMASK_  802816     // B*H*W
#define CHW_    802816     // C*H*W
#define NTOT_   51380224   // B*C*H*W
#define NV4_    12845056   // NTOT/4

__device__ __forceinline__ uint32_t rotl32(uint32_t x, int d) {
  return (x << d) | (x >> (32 - d));
}

// Threefry-2x32, key=(0,42). Partitionable JAX layout: counter = (0, i),
// 32-bit output = x0 ^ x1.
// (Fallback if harness JAX predates partitionable default: bits[i] =
//  y0(i, i+N/2) for i<N/2 else y1(i-N/2, i) — switch counter init + no xor.)
__device__ __forceinline__ uint32_t threefry_bits(uint32_t i) {
  const uint32_t k0 = 0u, k1 = 42u;
  const uint32_t k2 = k0 ^ k1 ^ 0x1BD11BDAu;
  uint32_t x0 = 0u, x1 = i;
  x0 += k0; x1 += k1;
#define TF_R(r) { x0 += x1; x1 = rotl32(x1, (r)); x1 ^= x0; }
  TF_R(13) TF_R(15) TF_R(26) TF_R(6)
  x0 += k1; x1 += k2 + 1u;
  TF_R(17) TF_R(29) TF_R(16) TF_R(24)
  x0 += k2; x1 += k0 + 2u;
  TF_R(13) TF_R(15) TF_R(26) TF_R(6)
  x0 += k0; x1 += k1 + 3u;
  TF_R(17) TF_R(29) TF_R(16) TF_R(24)
  x0 += k1; x1 += k2 + 4u;
  TF_R(13) TF_R(15) TF_R(26) TF_R(6)
  x0 += k2; x1 += k0 + 5u;
#undef TF_R
  return x0 ^ x1;
}

__global__ void k_init_mask(uint8_t* __restrict__ init,
                            double* __restrict__ sum, float p) {
  int i = blockIdx.x * blockDim.x + threadIdx.x;
  if (i == 0) *sum = 0.0;            // ws is poisoned 0xAA every call
  if (i >= NMASK_) return;
  uint32_t bits = threefry_bits((uint32_t)i);
  float u = __uint_as_float((bits >> 9) | 0x3f800000u) - 1.0f;  // [0,1)
  init[i] = (u < p) ? (uint8_t)1 : (uint8_t)0;
}

// rows: tmp[b,a,j] = AND_{i=a-2..a+3 clamped} init[b,i,j]
__global__ void k_erode_rows(const uint8_t* __restrict__ init,
                             uint8_t* __restrict__ tmp) {
  int t = blockIdx.x * blockDim.x + threadIdx.x;
  if (t >= NMASK_) return;
  int b = t / HW_;
  int rem = t - b * HW_;
  int a = rem / W_;
  int j = rem - a * W_;
  int lo = a - 2; if (lo < 0) lo = 0;
  int hi = a + 3; if (hi > H_ - 1) hi = H_ - 1;
  const uint8_t* base = init + b * HW_ + j;
  unsigned v = 1u;
  for (int i = lo; i <= hi; ++i) v &= base[i * W_];
  tmp[t] = (uint8_t)v;
}

// cols: mask[b,a,j] = AND_{jj=j-2..j+3 clamped} tmp[b,a,jj]
__global__ void k_erode_cols(const uint8_t* __restrict__ tmp,
                             uint8_t* __restrict__ mask) {
  int t = blockIdx.x * blockDim.x + threadIdx.x;
  if (t >= NMASK_) return;
  int b = t / HW_;
  int rem = t - b * HW_;
  int a = rem / W_;
  int j = rem - a * W_;
  int lo = j - 2; if (lo < 0) lo = 0;
  int hi = j + 3; if (hi > W_ - 1) hi = W_ - 1;
  const uint8_t* row = tmp + b * HW_ + a * W_;
  unsigned v = 1u;
  for (int jj = lo; jj <= hi; ++jj) v &= row[jj];
  mask[t] = (uint8_t)v;
}

__global__ void k_sum(const float4* __restrict__ x4,
                      const uint8_t* __restrict__ mask,
                      double* __restrict__ sum) {
  float acc = 0.0f;
  int stride = gridDim.x * blockDim.x;
  for (int f = blockIdx.x * blockDim.x + threadIdx.x; f < NV4_; f += stride) {
    float4 v = x4[f];
    int e = f << 2;
    int b = e / CHW_;
    int hw = (e - b * CHW_) % HW_;          // 4 consecutive bytes, 4-aligned
    uint32_t mw = *(const uint32_t*)(mask + b * HW_ + hw);
    acc += (mw & 0x000000ffu) ? v.x : 0.0f;
    acc += (mw & 0x0000ff00u) ? v.y : 0.0f;
    acc += (mw & 0x00ff0000u) ? v.z : 0.0f;
    acc += (mw & 0xff000000u) ? v.w : 0.0f;
  }
  for (int off = 32; off > 0; off >>= 1)
    acc += __shfl_down(acc, off, 64);
  __shared__ float part[4];                  // 256 threads = 4 waves
  int lane = threadIdx.x & 63;
  int wv = threadIdx.x >> 6;
  if (lane == 0) part[wv] = acc;
  __syncthreads();
  if (threadIdx.x == 0)
    atomicAdd(sum, (double)(part[0] + part[1] + part[2] + part[3]));
}

__global__ void k_scale(const float4* __restrict__ x4,
                        const uint8_t* __restrict__ mask,
                        const double* __restrict__ sum,
                        float4* __restrict__ out4) {
  float s = (float)(*sum);
  float scale = 802816.0f / s;               // N/sum, ~1ulp vs (x*N)/s
  int stride = gridDim.x * blockDim.x;
  for (int f = blockIdx.x * blockDim.x + threadIdx.x; f < NV4_; f += stride) {
    float4 v = x4[f];
    int e = f << 2;
    int b = e / CHW_;
    int hw = (e - b * CHW_) % HW_;
    uint32_t mw = *(const uint32_t*)(mask + b * HW_ + hw);
    float4 o;
    o.x = (mw & 0x000000ffu) ? v.x * scale : 0.0f;
    o.y = (mw & 0x0000ff00u) ? v.y * scale : 0.0f;
    o.z = (mw & 0x00ff0000u) ? v.z * scale : 0.0f;
    o.w = (mw & 0xff000000u) ? v.w * scale : 0.0f;
    out4[f] = o;
  }
}

extern "C" void kernel_launch(void* const* d_in, const int* in_sizes, int n_in,
                              void* d_out, int out_size, void* d_ws, size_t ws_size,
                              hipStream_t stream) {
  const float* x = (const float*)d_in[0];
  float* out = (float*)d_out;
  char* ws = (char*)d_ws;
  double* sum = (double*)ws;                 // 8B @ offset 0
  uint8_t* mA = (uint8_t*)(ws + 16);         // init mask, then final mask
  uint8_t* mB = mA + NMASK_;                 // row-eroded tmp
  // total ws use: 16 + 2*802816 ≈ 1.6 MB

  // gamma exactly as Python evaluates it: ((1.0-0.9) * (H**2)) / (bs**2*(H-bs+1)**2)
  double gamma = (1.0 - 0.9) * 12544.0 / 550564.0;
  float p = (float)(1.0 - gamma);            // keep-prob, float32 like JAX's `u < p`

  int mblk = (NMASK_ + 255) / 256;
  k_init_mask<<<mblk, 256, 0, stream>>>(mA, sum, p);
  k_erode_rows<<<mblk, 256, 0, stream>>>(mA, mB);
  k_erode_cols<<<mblk, 256, 0, stream>>>(mB, mA);
  k_sum<<<2048, 256, 0, stream>>>((const float4*)x, mA, sum);
  k_scale<<<8192, 256, 0, stream>>>((const float4*)x, mA, sum, (float4*)out);
}

// Round 3
// 394.230 us; speedup vs baseline: 1.0103x; 1.0103x over previous
//
#include <hip/hip_runtime.h>
#include <stdint.h>

// DropBlock: x:(64,64,112,112) f32. mask over (B,H,W) from JAX threefry
// bernoulli(seed 42) [partitionable layout, verified R1], eroded by 6x6 min
// window (pad (2,3)), out = x*mask * (B*H*W)/sum(x*mask).
#define B_      64
#define H_      112
#define W_      112
#define HW_     12544      // H*W
#define CHW_    802816     // C*H*W
#define NV4_    12845056   // B*C*H*W / 4
#define NSUMBLK 2048

typedef float v4f __attribute__((ext_vector_type(4)));  // NT-store-compatible

__device__ __forceinline__ uint32_t rotl32(uint32_t x, int d) {
  return (x << d) | (x >> (32 - d));
}

// Threefry-2x32, key=(0,42), counter=(0,i), out = x0^x1 (partitionable JAX).
__device__ __forceinline__ uint32_t threefry_bits(uint32_t i) {
  const uint32_t k0 = 0u, k1 = 42u;
  const uint32_t k2 = k0 ^ k1 ^ 0x1BD11BDAu;
  uint32_t x0 = 0u, x1 = i;
  x0 += k0; x1 += k1;
#define TF_R(r) { x0 += x1; x1 = rotl32(x1, (r)); x1 ^= x0; }
  TF_R(13) TF_R(15) TF_R(26) TF_R(6)
  x0 += k1; x1 += k2 + 1u;
  TF_R(17) TF_R(29) TF_R(16) TF_R(24)
  x0 += k2; x1 += k0 + 2u;
  TF_R(13) TF_R(15) TF_R(26) TF_R(6)
  x0 += k0; x1 += k1 + 3u;
  TF_R(17) TF_R(29) TF_R(16) TF_R(24)
  x0 += k1; x1 += k2 + 4u;
  TF_R(13) TF_R(15) TF_R(26) TF_R(6)
  x0 += k2; x1 += k0 + 5u;
#undef TF_R
  return x0 ^ x1;
}

// Fused: threefry bernoulli -> LDS, row-erode -> LDS, col-erode -> global mask.
// One block per batch image b (112x112 = 12544 cells), 1024 threads, 25 KB LDS.
__global__ __launch_bounds__(1024) void k_mask(uint8_t* __restrict__ mask,
                                               float p) {
  __shared__ uint8_t t0[HW_];
  __shared__ uint8_t t1[HW_];
  const int b = blockIdx.x;
  const int tid = threadIdx.x;
  for (int c = tid; c < HW_; c += 1024) {
    uint32_t bits = threefry_bits((uint32_t)(b * HW_ + c));
    float u = __uint_as_float((bits >> 9) | 0x3f800000u) - 1.0f;  // [0,1)
    t0[c] = (u < p) ? (uint8_t)1 : (uint8_t)0;
  }
  __syncthreads();
  for (int c = tid; c < HW_; c += 1024) {      // erode along H
    int a = c / W_, j = c - a * W_;
    int lo = a - 2; if (lo < 0) lo = 0;
    int hi = a + 3; if (hi > H_ - 1) hi = H_ - 1;
    unsigned v = 1u;
    for (int i = lo; i <= hi; ++i) v &= t0[i * W_ + j];
    t1[c] = (uint8_t)v;
  }
  __syncthreads();
  for (int c = tid; c < HW_; c += 1024) {      // erode along W
    int a = c / W_, j = c - a * W_;
    int lo = j - 2; if (lo < 0) lo = 0;
    int hi = j + 3; if (hi > W_ - 1) hi = W_ - 1;
    unsigned v = 1u;
    for (int jj = lo; jj <= hi; ++jj) v &= t1[a * W_ + jj];
    mask[b * HW_ + c] = (uint8_t)v;
  }
}

// Masked sum of x -> one float partial per block (no atomics).
__global__ __launch_bounds__(256) void k_sum(const float4* __restrict__ x4,
                                             const uint8_t* __restrict__ mask,
                                             float* __restrict__ partials) {
  float acc = 0.0f;
  const int stride = NSUMBLK * 256;
  for (int f = blockIdx.x * 256 + threadIdx.x; f < NV4_; f += stride) {
    float4 v = x4[f];
    int e = f << 2;
    int b = e / CHW_;
    int hw = (e - b * CHW_) % HW_;             // 4 consecutive mask bytes
    uint32_t mw = *(const uint32_t*)(mask + b * HW_ + hw);
    acc += (mw & 0x000000ffu) ? v.x : 0.0f;
    acc += (mw & 0x0000ff00u) ? v.y : 0.0f;
    acc += (mw & 0x00ff0000u) ? v.z : 0.0f;
    acc += (mw & 0xff000000u) ? v.w : 0.0f;
  }
  for (int off = 32; off > 0; off >>= 1)
    acc += __shfl_down(acc, off, 64);
  __shared__ float part[4];
  if ((threadIdx.x & 63) == 0) part[threadIdx.x >> 6] = acc;
  __syncthreads();
  if (threadIdx.x == 0)
    partials[blockIdx.x] = part[0] + part[1] + part[2] + part[3];
}

// Reduce 2048 partials (double accum) -> scale = (B*H*W)/sum, one block.
__global__ __launch_bounds__(256) void k_fin(const float* __restrict__ partials,
                                             float* __restrict__ scale) {
  double acc = 0.0;
  for (int i = threadIdx.x; i < NSUMBLK; i += 256)
    acc += (double)partials[i];
  for (int off = 32; off > 0; off >>= 1)
    acc += __shfl_down(acc, off, 64);
  __shared__ double part[4];
  if ((threadIdx.x & 63) == 0) part[threadIdx.x >> 6] = acc;
  __syncthreads();
  if (threadIdx.x == 0) {
    double s = part[0] + part[1] + part[2] + part[3];
    *scale = (float)(802816.0 / s);
  }
}

// out = x*mask*scale. Nontemporal stores keep x L3-resident for this pass.
__global__ __launch_bounds__(256) void k_scale(const float4* __restrict__ x4,
                                               const uint8_t* __restrict__ mask,
                                               const float* __restrict__ scalep,
                                               v4f* __restrict__ out4) {
  const float scale = *scalep;
  const int stride = gridDim.x * 256;
  for (int f = blockIdx.x * 256 + threadIdx.x; f < NV4_; f += stride) {
    float4 v = x4[f];
    int e = f << 2;
    int b = e / CHW_;
    int hw = (e - b * CHW_) % HW_;
    uint32_t mw = *(const uint32_t*)(mask + b * HW_ + hw);
    v4f o;
    o.x = (mw & 0x000000ffu) ? v.x * scale : 0.0f;
    o.y = (mw & 0x0000ff00u) ? v.y * scale : 0.0f;
    o.z = (mw & 0x00ff0000u) ? v.z * scale : 0.0f;
    o.w = (mw & 0xff000000u) ? v.w * scale : 0.0f;
    __builtin_nontemporal_store(o, &out4[f]);
  }
}

extern "C" void kernel_launch(void* const* d_in, const int* in_sizes, int n_in,
                              void* d_out, int out_size, void* d_ws, size_t ws_size,
                              hipStream_t stream) {
  const float* x = (const float*)d_in[0];
  float* out = (float*)d_out;
  char* ws = (char*)d_ws;
  float* scale = (float*)ws;                   // 4B   @ 0
  float* partials = (float*)(ws + 16);         // 8KB  @ 16
  uint8_t* mask = (uint8_t*)(ws + 16384);      // 0.8MB@ 16K
  // (partials fully overwritten by k_sum each call; poison-safe, no memset)

  // gamma exactly as Python: (1.0-0.9) * H^2 / (bs^2 * (H-bs+1)^2)
  double gamma = (1.0 - 0.9) * 12544.0 / 550564.0;
  float p = (float)(1.0 - gamma);              // f32 compare like JAX `u < p`

  k_mask <<<B_,      1024, 0, stream>>>(mask, p);
  k_sum  <<<NSUMBLK, 256,  0, stream>>>((const float4*)x, mask, partials);
  k_fin  <<<1,       256,  0, stream>>>(partials, scale);
  k_scale<<<8192,    256,  0, stream>>>((const float4*)x, mask, scale,
                                        (v4f*)out);
}